// Round 1
// baseline (726.380 us; speedup 1.0000x reference)
//
#include <hip/hip_runtime.h>
#include <math.h>

#define HID 2048
#define NH 32
#define NKV 8
#define HD 64
#define BB 2
#define SS 2048
#define MTOT (BB * SS) // 4096

typedef __bf16 bf16;
typedef __bf16 bf16x8 __attribute__((ext_vector_type(8)));
typedef __bf16 bf16x4 __attribute__((ext_vector_type(4)));
typedef float f32x4 __attribute__((ext_vector_type(4)));

#define MFMA16(a, b, c) __builtin_amdgcn_mfma_f32_16x16x32_bf16((a), (b), (c), 0, 0, 0)

__device__ __forceinline__ void load_lds16(const void* g, void* l) {
  __builtin_amdgcn_global_load_lds((const __attribute__((address_space(1))) void*)g,
                                   (__attribute__((address_space(3))) void*)l, 16, 0, 0);
}

// ---------------- fp32 -> bf16 convert ----------------
__global__ void cvt_kernel(const float* __restrict__ src, bf16* __restrict__ dst, int n) {
  int i = (blockIdx.x * 256 + threadIdx.x) * 4;
  if (i >= n) return;
  float4 v = *(const float4*)(src + i);
  bf16x4 o;
  o[0] = (bf16)v.x; o[1] = (bf16)v.y; o[2] = (bf16)v.z; o[3] = (bf16)v.w;
  *(bf16x4*)(dst + i) = o;
}

// ---------------- shared 128x128 GEMM core (C = A * W^T, K=2048) ----------------
// A: [M,2048] bf16 row-major (pre-offset to tile row base)
// W: [N,2048] bf16 row-major (pre-offset to tile row base)
__device__ __forceinline__ void gemm128_core(const bf16* __restrict__ Ap,
                                             const bf16* __restrict__ Wp,
                                             bf16* As, bf16* Bs, f32x4 acc[4][4]) {
  const int tid = threadIdx.x;
  const int w = tid >> 6, lane = tid & 63;
  const int sr = lane >> 2;          // row within a 16-row staging chunk
  const int scc = (lane & 3) * 8;    // bf16 col offset (16B per lane)
  const int l16 = lane & 15, quad = lane >> 4;
  const int mw = (w >> 1) * 64, nw = (w & 1) * 64;

  const bf16* gA = Ap + (size_t)(w * 32 + sr) * HID + scc;
  const bf16* gB = Wp + (size_t)(w * 32 + sr) * HID + scc;
  bf16* lA = As + (w * 32) * 32;
  bf16* lB = Bs + (w * 32) * 32;

  for (int k0 = 0; k0 < HID; k0 += 32) {
    load_lds16(gA + k0, lA);
    load_lds16(gA + k0 + (size_t)16 * HID, lA + 16 * 32);
    load_lds16(gB + k0, lB);
    load_lds16(gB + k0 + (size_t)16 * HID, lB + 16 * 32);
    __syncthreads();
    bf16x8 af[4], bfr[4];
#pragma unroll
    for (int mi = 0; mi < 4; ++mi)
      af[mi] = *(const bf16x8*)&As[(mw + mi * 16 + l16) * 32 + quad * 8];
#pragma unroll
    for (int ni = 0; ni < 4; ++ni)
      bfr[ni] = *(const bf16x8*)&Bs[(nw + ni * 16 + l16) * 32 + quad * 8];
#pragma unroll
    for (int mi = 0; mi < 4; ++mi)
#pragma unroll
      for (int ni = 0; ni < 4; ++ni)
        acc[mi][ni] = MFMA16(af[mi], bfr[ni], acc[mi][ni]);
    __syncthreads();
  }
}

// ---------------- fused QKV projection ----------------
// grid: (MTOT/128, 3072/128) ; N-space = [Q:2048 | K:512 | V:512]
__global__ __launch_bounds__(256) void gemm_qkv(const bf16* __restrict__ A,
                                                const bf16* __restrict__ Wq,
                                                const bf16* __restrict__ Wk,
                                                const bf16* __restrict__ Wv,
                                                bf16* __restrict__ Qb,
                                                bf16* __restrict__ Kb,
                                                bf16* __restrict__ Vt) {
  __shared__ bf16 As[128 * 32];
  __shared__ bf16 Bs[128 * 32];
  const int tileM = blockIdx.x * 128;
  const int n0 = blockIdx.y * 128;
  const bf16* Wp;
  int mode;
  if (n0 < HID) { Wp = Wq + (size_t)n0 * HID; mode = 0; }
  else if (n0 < HID + 512) { Wp = Wk + (size_t)(n0 - HID) * HID; mode = 1; }
  else { Wp = Wv + (size_t)(n0 - HID - 512) * HID; mode = 2; }

  f32x4 acc[4][4];
#pragma unroll
  for (int i = 0; i < 4; ++i)
#pragma unroll
    for (int j = 0; j < 4; ++j) acc[i][j] = (f32x4){0.f, 0.f, 0.f, 0.f};

  gemm128_core(A + (size_t)tileM * HID, Wp, As, Bs, acc);

  const int tid = threadIdx.x;
  const int w = tid >> 6, lane = tid & 63;
  const int l16 = lane & 15, quad = lane >> 4;
  const int mw = (w >> 1) * 64, nw = (w & 1) * 64;
#pragma unroll
  for (int mi = 0; mi < 4; ++mi) {
#pragma unroll
    for (int ni = 0; ni < 4; ++ni) {
#pragma unroll
      for (int r = 0; r < 4; ++r) {
        int grow = tileM + mw + mi * 16 + quad * 4 + r;
        int gcol = n0 + nw + ni * 16 + l16;
        float v = acc[mi][ni][r];
        int b = grow >> 11, spos = grow & (SS - 1);
        if (mode == 0) {
          Qb[(size_t)grow * HID + gcol] = (bf16)v;
        } else if (mode == 1) {
          int nk = gcol - HID;
          Kb[(((size_t)(b * NKV + (nk >> 6))) * SS + spos) * HD + (nk & 63)] = (bf16)v;
        } else {
          int nv = gcol - HID - 512;
          Vt[(((size_t)(b * NKV + (nv >> 6))) * HD + (nv & 63)) * SS + spos] = (bf16)v;
        }
      }
    }
  }
}

// ---------------- output projection ----------------
__global__ __launch_bounds__(256) void gemm_out(const bf16* __restrict__ A,
                                                const bf16* __restrict__ Wo,
                                                float* __restrict__ out) {
  __shared__ bf16 As[128 * 32];
  __shared__ bf16 Bs[128 * 32];
  const int tileM = blockIdx.x * 128;
  const int n0 = blockIdx.y * 128;
  f32x4 acc[4][4];
#pragma unroll
  for (int i = 0; i < 4; ++i)
#pragma unroll
    for (int j = 0; j < 4; ++j) acc[i][j] = (f32x4){0.f, 0.f, 0.f, 0.f};

  gemm128_core(A + (size_t)tileM * HID, Wo + (size_t)n0 * HID, As, Bs, acc);

  const int tid = threadIdx.x;
  const int w = tid >> 6, lane = tid & 63;
  const int l16 = lane & 15, quad = lane >> 4;
  const int mw = (w >> 1) * 64, nw = (w & 1) * 64;
#pragma unroll
  for (int mi = 0; mi < 4; ++mi)
#pragma unroll
    for (int ni = 0; ni < 4; ++ni)
#pragma unroll
      for (int r = 0; r < 4; ++r) {
        int grow = tileM + mw + mi * 16 + quad * 4 + r;
        int gcol = n0 + nw + ni * 16 + l16;
        out[(size_t)grow * HID + gcol] = acc[mi][ni][r];
      }
}

// ---------------- RoPE ----------------
__global__ void rope_q(bf16* __restrict__ Qb) {
  int idx = blockIdx.x * 256 + threadIdx.x;   // 2^22 threads
  int i = idx & 31;
  int h = (idx >> 5) & 31;
  int spos = (idx >> 10) & (SS - 1);
  int b = idx >> 21;
  bf16* p = Qb + ((size_t)(b * SS + spos)) * HID + h * HD;
  float x1 = (float)p[i], x2 = (float)p[i + 32];
  float ex = (float)i * (1.0f / 32.0f);
  float inv = 1.0f / powf(10000.0f, ex);
  float fr = (float)spos * inv;
  float sn, cs;
  sincosf(fr, &sn, &cs);
  p[i] = (bf16)(x1 * cs - x2 * sn);
  p[i + 32] = (bf16)(x2 * cs + x1 * sn);
}

__global__ void rope_k(bf16* __restrict__ Kb) {
  int idx = blockIdx.x * 256 + threadIdx.x;   // 2^20 threads
  int i = idx & 31;
  int spos = (idx >> 5) & (SS - 1);
  int kvh = (idx >> 16) & 7;
  int b = idx >> 19;
  bf16* p = Kb + (((size_t)(b * NKV + kvh)) * SS + spos) * HD;
  float x1 = (float)p[i], x2 = (float)p[i + 32];
  float ex = (float)i * (1.0f / 32.0f);
  float inv = 1.0f / powf(10000.0f, ex);
  float fr = (float)spos * inv;
  float sn, cs;
  sincosf(fr, &sn, &cs);
  p[i] = (bf16)(x1 * cs - x2 * sn);
  p[i + 32] = (bf16)(x2 * cs + x1 * sn);
}

// ---------------- flash attention (causal, GQA) ----------------
// grid: (SS/64, BB*NH); block 256 (4 waves); wave w owns q-rows [q0+16w, q0+16w+16)
__global__ __launch_bounds__(256) void attn(const bf16* __restrict__ Qb,
                                            const bf16* __restrict__ Kb,
                                            const bf16* __restrict__ Vt,
                                            bf16* __restrict__ Ctx) {
  __shared__ bf16 Pbuf[4][16 * 80];
  const int tid = threadIdx.x;
  const int w = tid >> 6, lane = tid & 63;
  const int l16 = lane & 15, quad = lane >> 4;
  const int bh = blockIdx.y, b = bh >> 5, h = bh & 31, kvh = h >> 2;
  const int qt = blockIdx.x, q0 = qt * 64;
  bf16* Pw = &Pbuf[w][0];

  const bf16* Qp = Qb + ((size_t)(b * SS + q0 + w * 16 + l16)) * HID + h * HD + quad * 8;
  bf16x8 qa0 = *(const bf16x8*)Qp;
  bf16x8 qa1 = *(const bf16x8*)(Qp + 32);

  float m_r[4], l_r[4];
  f32x4 oacc[4];
#pragma unroll
  for (int r = 0; r < 4; ++r) { m_r[r] = -1e30f; l_r[r] = 0.f; }
#pragma unroll
  for (int d = 0; d < 4; ++d) oacc[d] = (f32x4){0.f, 0.f, 0.f, 0.f};

  const bf16* Kbase = Kb + ((size_t)(b * NKV + kvh)) * SS * HD;
  const bf16* Vbase = Vt + ((size_t)(b * NKV + kvh)) * HD * SS;

  for (int kt = 0; kt <= qt; ++kt) {
    const int kb = kt * 64;
    f32x4 sc[4];
#pragma unroll
    for (int nt = 0; nt < 4; ++nt) {
      const bf16* Kp = Kbase + (size_t)(kb + nt * 16 + l16) * HD + quad * 8;
      bf16x8 kf0 = *(const bf16x8*)Kp;
      bf16x8 kf1 = *(const bf16x8*)(Kp + 32);
      f32x4 s = {0.f, 0.f, 0.f, 0.f};
      s = MFMA16(qa0, kf0, s);
      s = MFMA16(qa1, kf1, s);
      s *= 0.125f;
      if (kt == qt) {
        const int key = kb + nt * 16 + l16;
#pragma unroll
        for (int r = 0; r < 4; ++r) {
          int qr = q0 + w * 16 + quad * 4 + r;
          if (key > qr) s[r] = -1e9f;
        }
      }
      sc[nt] = s;
    }
    // online softmax (rows live on the 16 lanes of each quad)
    float alpha[4];
#pragma unroll
    for (int r = 0; r < 4; ++r) {
      float m = fmaxf(fmaxf(sc[0][r], sc[1][r]), fmaxf(sc[2][r], sc[3][r]));
#pragma unroll
      for (int off = 1; off < 16; off <<= 1) m = fmaxf(m, __shfl_xor(m, off, 16));
      float mn = fmaxf(m, m_r[r]);
      alpha[r] = __expf(m_r[r] - mn);
      m_r[r] = mn;
      l_r[r] *= alpha[r];
    }
#pragma unroll
    for (int d = 0; d < 4; ++d)
#pragma unroll
      for (int r = 0; r < 4; ++r) oacc[d][r] *= alpha[r];

    float rs[4] = {0.f, 0.f, 0.f, 0.f};
#pragma unroll
    for (int nt = 0; nt < 4; ++nt)
#pragma unroll
      for (int r = 0; r < 4; ++r) {
        float p = __expf(sc[nt][r] - m_r[r]);
        rs[r] += p;
        Pw[(quad * 4 + r) * 80 + nt * 16 + l16] = (bf16)p;
      }
#pragma unroll
    for (int r = 0; r < 4; ++r) {
      float t = rs[r];
#pragma unroll
      for (int off = 1; off < 16; off <<= 1) t += __shfl_xor(t, off, 16);
      l_r[r] += t;
    }
    __syncthreads();
    bf16x8 p0 = *(const bf16x8*)&Pw[l16 * 80 + quad * 8];
    bf16x8 p1 = *(const bf16x8*)&Pw[l16 * 80 + 32 + quad * 8];
#pragma unroll
    for (int dn = 0; dn < 4; ++dn) {
      const bf16* Vp = Vbase + (size_t)(dn * 16 + l16) * SS + kb + quad * 8;
      bf16x8 v0 = *(const bf16x8*)Vp;
      bf16x8 v1 = *(const bf16x8*)(Vp + 32);
      oacc[dn] = MFMA16(p0, v0, oacc[dn]);
      oacc[dn] = MFMA16(p1, v1, oacc[dn]);
    }
    __syncthreads();
  }
#pragma unroll
  for (int r = 0; r < 4; ++r) {
    float inv = 1.0f / l_r[r];
    int grow = q0 + w * 16 + quad * 4 + r;
    bf16* Cp = Ctx + ((size_t)(b * SS + grow)) * HID + h * HD + l16;
#pragma unroll
    for (int dn = 0; dn < 4; ++dn) Cp[dn * 16] = (bf16)(oacc[dn][r] * inv);
  }
}

// ---------------- launch ----------------
extern "C" void kernel_launch(void* const* d_in, const int* in_sizes, int n_in,
                              void* d_out, int out_size, void* d_ws, size_t ws_size,
                              hipStream_t stream) {
  const float* hs = (const float*)d_in[0];
  // d_in[1] = attention_mask (pure causal, implemented analytically)
  const float* Wq = (const float*)d_in[2];
  const float* Wk = (const float*)d_in[3];
  const float* Wv = (const float*)d_in[4];
  const float* Wo = (const float*)d_in[5];

  char* ws = (char*)d_ws;
  bf16* A_b  = (bf16*)(ws);              // 16 MB ; reused as Ctx after QKV gemm
  bf16* Wq_b = (bf16*)(ws + 16777216);   // 8 MB
  bf16* Wk_b = (bf16*)(ws + 25165824);   // 2 MB
  bf16* Wv_b = (bf16*)(ws + 27262976);   // 2 MB
  bf16* Wo_b = (bf16*)(ws + 29360128);   // 8 MB
  bf16* Qb   = (bf16*)(ws + 37748736);   // 16 MB
  bf16* Kb   = (bf16*)(ws + 54525952);   // 4 MB
  bf16* Vt   = (bf16*)(ws + 58720256);   // 4 MB  (end: 62914560)
  bf16* Ctx  = A_b;                      // alias: A dead after gemm_qkv

  cvt_kernel<<<8192, 256, 0, stream>>>(hs, A_b, MTOT * HID);
  cvt_kernel<<<4096, 256, 0, stream>>>(Wq, Wq_b, HID * HID);
  cvt_kernel<<<1024, 256, 0, stream>>>(Wk, Wk_b, 512 * HID);
  cvt_kernel<<<1024, 256, 0, stream>>>(Wv, Wv_b, 512 * HID);
  cvt_kernel<<<4096, 256, 0, stream>>>(Wo, Wo_b, HID * HID);

  gemm_qkv<<<dim3(MTOT / 128, 24), 256, 0, stream>>>(A_b, Wq_b, Wk_b, Wv_b, Qb, Kb, Vt);
  rope_q<<<16384, 256, 0, stream>>>(Qb);
  rope_k<<<4096, 256, 0, stream>>>(Kb);
  attn<<<dim3(SS / 64, BB * NH), 256, 0, stream>>>(Qb, Kb, Vt, Ctx);
  gemm_out<<<dim3(MTOT / 128, HID / 128), 256, 0, stream>>>(Ctx, Wo_b, (float*)d_out);
}

// Round 2
// 515.987 us; speedup vs baseline: 1.4077x; 1.4077x over previous
//
#include <hip/hip_runtime.h>
#include <math.h>

#define HID 2048
#define NH 32
#define NKV 8
#define HD 64
#define BB 2
#define SS 2048
#define MTOT (BB * SS) // 4096

typedef __bf16 bf16;
typedef __bf16 bf16x8 __attribute__((ext_vector_type(8)));
typedef __bf16 bf16x4 __attribute__((ext_vector_type(4)));
typedef float f32x4 __attribute__((ext_vector_type(4)));

#define MFMA16(a, b, c) __builtin_amdgcn_mfma_f32_16x16x32_bf16((a), (b), (c), 0, 0, 0)

__device__ __forceinline__ void load_lds16(const void* g, void* l) {
  __builtin_amdgcn_global_load_lds((const __attribute__((address_space(1))) void*)g,
                                   (__attribute__((address_space(3))) void*)l, 16, 0, 0);
}

// ---------------- fp32 -> bf16 convert ----------------
__global__ void cvt_kernel(const float* __restrict__ src, bf16* __restrict__ dst, int n) {
  int i = (blockIdx.x * 256 + threadIdx.x) * 4;
  if (i >= n) return;
  float4 v = *(const float4*)(src + i);
  bf16x4 o;
  o[0] = (bf16)v.x; o[1] = (bf16)v.y; o[2] = (bf16)v.z; o[3] = (bf16)v.w;
  *(bf16x4*)(dst + i) = o;
}

// ---------------- shared 128x128 GEMM core (C = A * W^T, K=2048) ----------------
__device__ __forceinline__ void gemm128_core(const bf16* __restrict__ Ap,
                                             const bf16* __restrict__ Wp,
                                             bf16* As, bf16* Bs, f32x4 acc[4][4]) {
  const int tid = threadIdx.x;
  const int w = tid >> 6, lane = tid & 63;
  const int sr = lane >> 2;          // row within a 16-row staging chunk
  const int scc = (lane & 3) * 8;    // bf16 col offset (16B per lane)
  const int l16 = lane & 15, quad = lane >> 4;
  const int mw = (w >> 1) * 64, nw = (w & 1) * 64;

  const bf16* gA = Ap + (size_t)(w * 32 + sr) * HID + scc;
  const bf16* gB = Wp + (size_t)(w * 32 + sr) * HID + scc;
  bf16* lA = As + (w * 32) * 32;
  bf16* lB = Bs + (w * 32) * 32;

  for (int k0 = 0; k0 < HID; k0 += 32) {
    load_lds16(gA + k0, lA);
    load_lds16(gA + k0 + (size_t)16 * HID, lA + 16 * 32);
    load_lds16(gB + k0, lB);
    load_lds16(gB + k0 + (size_t)16 * HID, lB + 16 * 32);
    __syncthreads();
    bf16x8 af[4], bfr[4];
#pragma unroll
    for (int mi = 0; mi < 4; ++mi)
      af[mi] = *(const bf16x8*)&As[(mw + mi * 16 + l16) * 32 + quad * 8];
#pragma unroll
    for (int ni = 0; ni < 4; ++ni)
      bfr[ni] = *(const bf16x8*)&Bs[(nw + ni * 16 + l16) * 32 + quad * 8];
#pragma unroll
    for (int mi = 0; mi < 4; ++mi)
#pragma unroll
      for (int ni = 0; ni < 4; ++ni)
        acc[mi][ni] = MFMA16(af[mi], bfr[ni], acc[mi][ni]);
    __syncthreads();
  }
}

// ---------------- fused QKV projection ----------------
__global__ __launch_bounds__(256) void gemm_qkv(const bf16* __restrict__ A,
                                                const bf16* __restrict__ Wq,
                                                const bf16* __restrict__ Wk,
                                                const bf16* __restrict__ Wv,
                                                bf16* __restrict__ Qb,
                                                bf16* __restrict__ Kb,
                                                bf16* __restrict__ Vt) {
  __shared__ bf16 As[128 * 32];
  __shared__ bf16 Bs[128 * 32];
  const int tileM = blockIdx.x * 128;
  const int n0 = blockIdx.y * 128;
  const bf16* Wp;
  int mode;
  if (n0 < HID) { Wp = Wq + (size_t)n0 * HID; mode = 0; }
  else if (n0 < HID + 512) { Wp = Wk + (size_t)(n0 - HID) * HID; mode = 1; }
  else { Wp = Wv + (size_t)(n0 - HID - 512) * HID; mode = 2; }

  f32x4 acc[4][4];
#pragma unroll
  for (int i = 0; i < 4; ++i)
#pragma unroll
    for (int j = 0; j < 4; ++j) acc[i][j] = (f32x4){0.f, 0.f, 0.f, 0.f};

  gemm128_core(A + (size_t)tileM * HID, Wp, As, Bs, acc);

  const int tid = threadIdx.x;
  const int w = tid >> 6, lane = tid & 63;
  const int l16 = lane & 15, quad = lane >> 4;
  const int mw = (w >> 1) * 64, nw = (w & 1) * 64;
#pragma unroll
  for (int mi = 0; mi < 4; ++mi) {
#pragma unroll
    for (int ni = 0; ni < 4; ++ni) {
#pragma unroll
      for (int r = 0; r < 4; ++r) {
        int grow = tileM + mw + mi * 16 + quad * 4 + r;
        int gcol = n0 + nw + ni * 16 + l16;
        float v = acc[mi][ni][r];
        int b = grow >> 11, spos = grow & (SS - 1);
        if (mode == 0) {
          Qb[(size_t)grow * HID + gcol] = (bf16)v;
        } else if (mode == 1) {
          int nk = gcol - HID;
          Kb[(((size_t)(b * NKV + (nk >> 6))) * SS + spos) * HD + (nk & 63)] = (bf16)v;
        } else {
          int nv = gcol - HID - 512;
          Vt[(((size_t)(b * NKV + (nv >> 6))) * HD + (nv & 63)) * SS + spos] = (bf16)v;
        }
      }
    }
  }
}

// ---------------- output projection ----------------
__global__ __launch_bounds__(256) void gemm_out(const bf16* __restrict__ A,
                                                const bf16* __restrict__ Wo,
                                                float* __restrict__ out) {
  __shared__ bf16 As[128 * 32];
  __shared__ bf16 Bs[128 * 32];
  const int tileM = blockIdx.x * 128;
  const int n0 = blockIdx.y * 128;
  f32x4 acc[4][4];
#pragma unroll
  for (int i = 0; i < 4; ++i)
#pragma unroll
    for (int j = 0; j < 4; ++j) acc[i][j] = (f32x4){0.f, 0.f, 0.f, 0.f};

  gemm128_core(A + (size_t)tileM * HID, Wo + (size_t)n0 * HID, As, Bs, acc);

  const int tid = threadIdx.x;
  const int w = tid >> 6, lane = tid & 63;
  const int l16 = lane & 15, quad = lane >> 4;
  const int mw = (w >> 1) * 64, nw = (w & 1) * 64;
#pragma unroll
  for (int mi = 0; mi < 4; ++mi)
#pragma unroll
    for (int ni = 0; ni < 4; ++ni)
#pragma unroll
      for (int r = 0; r < 4; ++r) {
        int grow = tileM + mw + mi * 16 + quad * 4 + r;
        int gcol = n0 + nw + ni * 16 + l16;
        out[(size_t)grow * HID + gcol] = acc[mi][ni][r];
      }
}

// ---------------- RoPE ----------------
__global__ void rope_q(bf16* __restrict__ Qb) {
  int idx = blockIdx.x * 256 + threadIdx.x;   // 2^22 threads
  int i = idx & 31;
  int h = (idx >> 5) & 31;
  int spos = (idx >> 10) & (SS - 1);
  int b = idx >> 21;
  bf16* p = Qb + ((size_t)(b * SS + spos)) * HID + h * HD;
  float x1 = (float)p[i], x2 = (float)p[i + 32];
  float ex = (float)i * (1.0f / 32.0f);
  float inv = 1.0f / powf(10000.0f, ex);
  float fr = (float)spos * inv;
  float sn, cs;
  sincosf(fr, &sn, &cs);
  p[i] = (bf16)(x1 * cs - x2 * sn);
  p[i + 32] = (bf16)(x2 * cs + x1 * sn);
}

__global__ void rope_k(bf16* __restrict__ Kb) {
  int idx = blockIdx.x * 256 + threadIdx.x;   // 2^20 threads
  int i = idx & 31;
  int spos = (idx >> 5) & (SS - 1);
  int kvh = (idx >> 16) & 7;
  int b = idx >> 19;
  bf16* p = Kb + (((size_t)(b * NKV + kvh)) * SS + spos) * HD;
  float x1 = (float)p[i], x2 = (float)p[i + 32];
  float ex = (float)i * (1.0f / 32.0f);
  float inv = 1.0f / powf(10000.0f, ex);
  float fr = (float)spos * inv;
  float sn, cs;
  sincosf(fr, &sn, &cs);
  p[i] = (bf16)(x1 * cs - x2 * sn);
  p[i + 32] = (bf16)(x2 * cs + x1 * sn);
}

// ---------------- flash attention v2 (causal, GQA, transposed S^T/O^T) ----------------
// grid: (16, BB*NH); block 256 (4 waves, NO cross-wave coupling, no barriers).
// Block x handles q-tiles {x, 31-x} (64 rows each) -> uniform 33 kt-iterations.
// S^T = K*Q^T: C col (lane&15) = q row  => softmax state is per-lane scalar.
// O^T = V^T*P^T accumulated in C layout; P round-trips a per-wave LDS buffer
// (stride 72 bf16: packed b64 writes / b128 reads, <=2-way bank alias).
#define PSTR 72
__global__ __launch_bounds__(256, 4) void attn(const bf16* __restrict__ Qb,
                                               const bf16* __restrict__ Kb,
                                               const bf16* __restrict__ Vt,
                                               bf16* __restrict__ Ctx) {
  __shared__ bf16 Pbuf[4][16 * PSTR];
  const int tid = threadIdx.x;
  const int w = tid >> 6, lane = tid & 63;
  const int l16 = lane & 15, quad = lane >> 4;
  const int bh = blockIdx.y, b = bh >> 5, h = bh & 31, kvh = h >> 2;
  bf16* Pw = &Pbuf[w][0];
  const bf16* Kbase = Kb + ((size_t)(b * NKV + kvh)) * SS * HD;
  const bf16* Vbase = Vt + ((size_t)(b * NKV + kvh)) * HD * SS;
  const int qrel = w * 16 + l16;
  const float sc_log2e = 0.125f * 1.44269504f; // 1/sqrt(64) * log2(e)

  for (int t = 0; t < 2; ++t) {
    const int qt = t ? (31 - (int)blockIdx.x) : (int)blockIdx.x;
    const int q0 = qt * 64;
    const int q = q0 + qrel;

    const bf16* Qp = Qb + ((size_t)(b * SS + q)) * HID + h * HD + quad * 8;
    bf16x8 qb0 = *(const bf16x8*)Qp;
    bf16x8 qb1 = *(const bf16x8*)(Qp + 32);

    float m = -1e30f, l = 0.f;
    f32x4 oacc[4];
#pragma unroll
    for (int d = 0; d < 4; ++d) oacc[d] = (f32x4){0.f, 0.f, 0.f, 0.f};

    for (int kt = 0; kt <= qt; ++kt) {
      const int kb = kt * 64;
      f32x4 sc[4];
#pragma unroll
      for (int nt = 0; nt < 4; ++nt) {
        const bf16* Kp = Kbase + (size_t)(kb + nt * 16 + l16) * HD + quad * 8;
        bf16x8 kf0 = *(const bf16x8*)Kp;
        bf16x8 kf1 = *(const bf16x8*)(Kp + 32);
        f32x4 s = {0.f, 0.f, 0.f, 0.f};
        s = MFMA16(kf0, qb0, s);   // S^T tile: row = key (quad*4+r), col = q (l16)
        s = MFMA16(kf1, qb1, s);
        s *= sc_log2e;             // log2-domain softmax
        if (kt == qt) {
          const int krel = nt * 16 + quad * 4;
#pragma unroll
          for (int r = 0; r < 4; ++r)
            if (krel + r > qrel) s[r] = -1e9f;
        }
        sc[nt] = s;
      }
      // per-lane row max over this lane's 16 keys, then combine across quads
      float mx = fmaxf(fmaxf(sc[0][0], sc[0][1]), fmaxf(sc[0][2], sc[0][3]));
#pragma unroll
      for (int nt = 1; nt < 4; ++nt)
        mx = fmaxf(mx, fmaxf(fmaxf(sc[nt][0], sc[nt][1]), fmaxf(sc[nt][2], sc[nt][3])));
      mx = fmaxf(mx, __shfl_xor(mx, 16));
      mx = fmaxf(mx, __shfl_xor(mx, 32));
      const float mn = fmaxf(m, mx);
      const float alpha = __builtin_amdgcn_exp2f(m - mn);
      m = mn;

      float rs = 0.f;
#pragma unroll
      for (int nt = 0; nt < 4; ++nt) {
        bf16x4 pk;
#pragma unroll
        for (int r = 0; r < 4; ++r) {
          float p = __builtin_amdgcn_exp2f(sc[nt][r] - m);
          rs += p;
          pk[r] = (bf16)p;
        }
        *(bf16x4*)&Pw[l16 * PSTR + nt * 16 + quad * 4] = pk;
      }
      rs += __shfl_xor(rs, 16);
      rs += __shfl_xor(rs, 32);
      l = l * alpha + rs;
#pragma unroll
      for (int dn = 0; dn < 4; ++dn) oacc[dn] *= alpha;

      bf16x8 p0 = *(const bf16x8*)&Pw[l16 * PSTR + quad * 8];
      bf16x8 p1 = *(const bf16x8*)&Pw[l16 * PSTR + 32 + quad * 8];
#pragma unroll
      for (int dn = 0; dn < 4; ++dn) {
        const bf16* Vp = Vbase + (size_t)(dn * 16 + l16) * SS + kb + quad * 8;
        bf16x8 v0 = *(const bf16x8*)Vp;
        bf16x8 v1 = *(const bf16x8*)(Vp + 32);
        oacc[dn] = MFMA16(v0, p0, oacc[dn]);  // O^T: row = d, col = q
        oacc[dn] = MFMA16(v1, p1, oacc[dn]);
      }
    }

    const float inv = 1.0f / l;
    bf16* Cp = Ctx + ((size_t)(b * SS + q)) * HID + h * HD + quad * 4;
#pragma unroll
    for (int dn = 0; dn < 4; ++dn) {
      bf16x4 ov;
#pragma unroll
      for (int r = 0; r < 4; ++r) ov[r] = (bf16)(oacc[dn][r] * inv);
      *(bf16x4*)(Cp + dn * 16) = ov;
    }
  }
}

// ---------------- launch ----------------
extern "C" void kernel_launch(void* const* d_in, const int* in_sizes, int n_in,
                              void* d_out, int out_size, void* d_ws, size_t ws_size,
                              hipStream_t stream) {
  const float* hs = (const float*)d_in[0];
  // d_in[1] = attention_mask (pure causal, implemented analytically)
  const float* Wq = (const float*)d_in[2];
  const float* Wk = (const float*)d_in[3];
  const float* Wv = (const float*)d_in[4];
  const float* Wo = (const float*)d_in[5];

  char* ws = (char*)d_ws;
  bf16* A_b  = (bf16*)(ws);              // 16 MB ; reused as Ctx after QKV gemm
  bf16* Wq_b = (bf16*)(ws + 16777216);   // 8 MB
  bf16* Wk_b = (bf16*)(ws + 25165824);   // 2 MB
  bf16* Wv_b = (bf16*)(ws + 27262976);   // 2 MB
  bf16* Wo_b = (bf16*)(ws + 29360128);   // 8 MB
  bf16* Qb   = (bf16*)(ws + 37748736);   // 16 MB
  bf16* Kb   = (bf16*)(ws + 54525952);   // 4 MB
  bf16* Vt   = (bf16*)(ws + 58720256);   // 4 MB  (end: 62914560)
  bf16* Ctx  = A_b;                      // alias: A dead after gemm_qkv

  cvt_kernel<<<8192, 256, 0, stream>>>(hs, A_b, MTOT * HID);
  cvt_kernel<<<4096, 256, 0, stream>>>(Wq, Wq_b, HID * HID);
  cvt_kernel<<<1024, 256, 0, stream>>>(Wk, Wk_b, 512 * HID);
  cvt_kernel<<<1024, 256, 0, stream>>>(Wv, Wv_b, 512 * HID);
  cvt_kernel<<<4096, 256, 0, stream>>>(Wo, Wo_b, HID * HID);

  gemm_qkv<<<dim3(MTOT / 128, 24), 256, 0, stream>>>(A_b, Wq_b, Wk_b, Wv_b, Qb, Kb, Vt);
  rope_q<<<16384, 256, 0, stream>>>(Qb);
  rope_k<<<4096, 256, 0, stream>>>(Kb);
  attn<<<dim3(16, BB * NH), 256, 0, stream>>>(Qb, Kb, Vt, Ctx);
  gemm_out<<<dim3(MTOT / 128, HID / 128), 256, 0, stream>>>(Ctx, Wo_b, (float*)d_out);
}